// Round 4
// baseline (14634.900 us; speedup 1.0000x reference)
//
#include <hip/hip_runtime.h>
#include <stdint.h>

// Speller: L=2048, N=32, T=200, V=34, IN=512, H=256, Q=256
// Dtype-adaptive: detects at runtime whether float tensors are f32 or bf16.
// Internally computes in bf16 MFMA + f32 accumulation; output written in detected dtype.

typedef __attribute__((ext_vector_type(8))) short short8;
typedef __attribute__((ext_vector_type(4))) short short4v;
typedef __attribute__((ext_vector_type(4))) float float4v;

__device__ __forceinline__ float b2f(unsigned short u) {
  union { unsigned u; float f; } x; x.u = ((unsigned)u) << 16; return x.f;
}
__device__ __forceinline__ unsigned short f2b(float f) {
  union { float f; unsigned u; } x; x.f = f;
  unsigned r = (x.u + 0x7fffu + ((x.u >> 16) & 1u)) >> 16;
  return (unsigned short)r;
}
__device__ __forceinline__ float sigm(float x) { return 1.f / (1.f + __expf(-x)); }
__device__ __forceinline__ float tanh_s(float x) { return 1.f - 2.f / (__expf(2.f * x) + 1.f); }

// ---------------- workspace layout (bytes) ----------------
static constexpr size_t OFF_K2   = 0;                      // bf16 [32][2048][256]
static constexpr size_t OFF_VAL  = OFF_K2  + 33554432;     // bf16 [32][2048][256]
static constexpr size_t OFF_WK2  = OFF_VAL + 33554432;     // bf16 [256][512]
static constexpr size_t OFF_BK2  = OFF_WK2 + 262144;       // f32 [256]
static constexpr size_t OFF_WKB  = OFF_BK2 + 1024;         // f32 [512]
static constexpr size_t OFF_BQBK = OFF_WKB + 2048;         // f32 [1]
static constexpr size_t OFF_KB   = OFF_BQBK + 256;         // f32 [32][2048]
static constexpr size_t OFF_CTXA = OFF_KB  + 262144;       // f32 [201][32][256]
static constexpr size_t OFF_CTXS = OFF_CTXA + 6586368;     // f32 [201][32]
static constexpr size_t OFF_H2A  = OFF_CTXS + 25856;       // bf16 [200][32][256]
static constexpr size_t OFF_HST  = OFF_H2A + 3276800;      // bf16 [3][2][32][256]
static constexpr size_t OFF_CST  = OFF_HST + 98304;        // f32 [3][32][256]
static constexpr size_t OFF_FLAG = OFF_CST + 98304;        // int flag (dtype)
// converted bf16 copies of float inputs (except seqs):
static constexpr size_t OFF_C    = OFF_FLAG + 256;
static constexpr size_t cEMB   = OFF_C;                // 34*256      -> 17408
static constexpr size_t cINITH = cEMB   + 17408;       // 768         -> 1536
static constexpr size_t cINITC = cINITH + 1536;        // 768         -> 1536
static constexpr size_t cWIH0  = cINITC + 1536;        // 1024*512    -> 1048576
static constexpr size_t cWHH0  = cWIH0  + 1048576;     // 1024*256    -> 524288
static constexpr size_t cBIH0  = cWHH0  + 524288;      // 1024        -> 2048
static constexpr size_t cBHH0  = cBIH0  + 2048;
static constexpr size_t cWIH1  = cBHH0  + 2048;        // 1024*256
static constexpr size_t cWHH1  = cWIH1  + 524288;
static constexpr size_t cBIH1  = cWHH1  + 524288;
static constexpr size_t cBHH1  = cBIH1  + 2048;
static constexpr size_t cWIH2  = cBHH1  + 2048;
static constexpr size_t cWHH2  = cWIH2  + 524288;
static constexpr size_t cBIH2  = cWHH2  + 524288;
static constexpr size_t cBHH2  = cBIH2  + 2048;
static constexpr size_t cWQ    = cBHH2  + 2048;        // 256*256     -> 131072
static constexpr size_t cBQ    = cWQ    + 131072;      // 256         -> 512
static constexpr size_t cWK    = cBQ    + 512;         // 256*512     -> 262144
static constexpr size_t cBK    = cWK    + 262144;      // 256         -> 512
static constexpr size_t cWV    = cBK    + 512;         // 256*512     -> 262144
static constexpr size_t cBV    = cWV    + 262144;      // 256         -> 512
static constexpr size_t cWO1   = cBV    + 512;         // 256*512     -> 262144
static constexpr size_t cBO1   = cWO1   + 262144;      // 256         -> 512
static constexpr size_t cBO2   = cBO1   + 512;         // 34          -> 128
static constexpr size_t WS_REQ = cBO2 + 128;           // ~82.4 MB

// ---------------- sentinel (ws too small diagnostic) ----------------
__global__ void k_sentinel(unsigned short* out, int n) {
  int i = blockIdx.x * 256 + threadIdx.x;
  if (i < n) out[i] = f2b(12345.0f);
}

// ---------------- dtype detector ----------------
// bf16 data: low halves of first 64 words are plausible 0.05*N values.
// f32 data: low halves are random mantissa bits -> implausible bf16.
__global__ void k_detect(const unsigned* __restrict__ seqw, int* flag) {
  int lane = threadIdx.x;  // 64 threads
  unsigned w = seqw[lane];
  float lo = b2f((unsigned short)(w & 0xFFFFu));
  float a = fabsf(lo);
  bool ok = (a > 1e-3f) && (a < 4.0f);
  unsigned long long m = __ballot(ok);
  if (lane == 0) *flag = (__popcll((unsigned long long)m) >= 32) ? 1 : 0;
}

// ---------------- bulk converter: 24 tensors ----------------
struct ConvList {
  const void* src[24];
  unsigned long long dstoff[24];
  int n[24];
};
__global__ void k_conv(ConvList cl, char* ws, const int* __restrict__ flag) {
  const int ti = blockIdx.y;
  const int i = blockIdx.x * 256 + threadIdx.x;
  const int n = cl.n[ti];
  if (i >= n) return;
  unsigned short* dst = (unsigned short*)(ws + cl.dstoff[ti]);
  if (*flag) dst[i] = ((const unsigned short*)cl.src[ti])[i];
  else       dst[i] = f2b(((const float*)cl.src[ti])[i]);
}

// ---------------- P0: fold Wq into Wk (consumes converted bf16) ----------------
__global__ void k_p0(const unsigned short* __restrict__ Wq, const unsigned short* __restrict__ Wk,
                     const unsigned short* __restrict__ bq, const unsigned short* __restrict__ bk,
                     unsigned short* Wk2, float* bk2, float* wkb, float* bqbk) {
  int wg = blockIdx.x, tid = threadIdx.x;
  if (wg < 512) {
    int idx = wg * 256 + tid;
    int h = idx >> 9, j = idx & 511;
    float acc = 0.f;
    for (int i = 0; i < 256; ++i) acc += b2f(Wq[i * 256 + h]) * b2f(Wk[i * 512 + j]);
    Wk2[h * 512 + j] = f2b(acc);
  } else if (wg == 512) {
    float acc = 0.f;
    for (int i = 0; i < 256; ++i) acc += b2f(bk[i]) * b2f(Wq[i * 256 + tid]);
    bk2[tid] = acc;
  } else if (wg == 513) {
    for (int j = tid; j < 512; j += 256) {
      float acc = 0.f;
      for (int i = 0; i < 256; ++i) acc += b2f(bq[i]) * b2f(Wk[i * 512 + j]);
      wkb[j] = acc;
    }
  } else {
    if (tid == 0) {
      float acc = 0.f;
      for (int i = 0; i < 256; ++i) acc += b2f(bq[i]) * b2f(bk[i]);
      *bqbk = acc;
    }
  }
}

// ---------------- init (seqs dtype-branch) ----------------
__global__ void k_init(const void* __restrict__ seqsv, const int* __restrict__ flag,
                       const unsigned short* __restrict__ inith, const unsigned short* __restrict__ initc,
                       const float* __restrict__ wkb, const float* __restrict__ bqbk, float* KB,
                       float* ctxacc, float* ctxsum, unsigned short* hst, float* cst) {
  int gid = blockIdx.x * 256 + threadIdx.x;  // 131072 threads
  for (int i = gid; i < 201 * 8192; i += 131072) ctxacc[i] = 0.f;
  if (gid < 6432) ctxsum[gid] = 0.f;
  if (gid < 8192) {
    int j = gid & 255;
    for (int Lr = 0; Lr < 3; ++Lr) {
      unsigned short hv = inith[Lr * 256 + j];
      hst[Lr * 16384 + gid] = hv;
      hst[Lr * 16384 + 8192 + gid] = hv;
      cst[Lr * 8192 + gid] = b2f(initc[Lr * 256 + j]);
    }
  }
  if (gid < 65536) {
    int l = gid >> 5, n = gid & 31;
    float acc = *bqbk;
    if (*flag) {
      const short8* row = (const short8*)((const unsigned short*)seqsv + (size_t)gid * 512);
      for (int jj = 0; jj < 64; ++jj) {
        short8 s = row[jj];
        #pragma unroll
        for (int e = 0; e < 8; ++e) acc += b2f((unsigned short)s[e]) * wkb[jj * 8 + e];
      }
    } else {
      const float4v* row = (const float4v*)((const float*)seqsv + (size_t)gid * 512);
      for (int jj = 0; jj < 128; ++jj) {
        float4v s = row[jj];
        acc += s.x * wkb[jj * 4 + 0] + s.y * wkb[jj * 4 + 1]
             + s.z * wkb[jj * 4 + 2] + s.w * wkb[jj * 4 + 3];
      }
    }
    KB[n * 2048 + l] = acc;
  }
}

// ---------------- P1: big GEMM  K2/VAL = seqs @ {Wk2,Wv}^T + bias ----------------
__global__ __launch_bounds__(256) void k_gemm(
    const void* __restrict__ Aseqv, const int* __restrict__ flag,
    const unsigned short* __restrict__ Wk2,
    const unsigned short* __restrict__ Wv, const float* __restrict__ bk2,
    const unsigned short* __restrict__ bv, unsigned short* __restrict__ K2,
    unsigned short* __restrict__ VALo) {
  __shared__ short As[5120];  // 128 x 40 (pad) bf16
  __shared__ short Bs[5120];
  const int tid = threadIdx.x;
  const int lane = tid & 63, wid = tid >> 6;
  const int c0 = blockIdx.x * 128;
  const int m0 = blockIdx.y * 128;
  const unsigned short* Wb = (c0 < 256) ? Wk2 : Wv;
  const int cb = c0 & 255;
  const int srow = tid >> 1, skh = (tid & 1) * 16;
  const int m = lane & 15, q = lane >> 4;
  const bool isf32 = (*flag == 0);

  float4v zero = {0.f, 0.f, 0.f, 0.f};
  float4v acc[2][8];
  for (int i = 0; i < 2; ++i) for (int j = 0; j < 8; ++j) acc[i][j] = zero;

  for (int it = 0; it < 16; ++it) {
    const int k0 = it * 32;
    if (isf32) {
      const float4v* sa = (const float4v*)((const float*)Aseqv + (size_t)(m0 + srow) * 512 + k0 + skh);
      float4v u0 = sa[0], u1 = sa[1], u2 = sa[2], u3 = sa[3];
      short8 s0, s1;
      s0[0]=(short)f2b(u0.x); s0[1]=(short)f2b(u0.y); s0[2]=(short)f2b(u0.z); s0[3]=(short)f2b(u0.w);
      s0[4]=(short)f2b(u1.x); s0[5]=(short)f2b(u1.y); s0[6]=(short)f2b(u1.z); s0[7]=(short)f2b(u1.w);
      s1[0]=(short)f2b(u2.x); s1[1]=(short)f2b(u2.y); s1[2]=(short)f2b(u2.z); s1[3]=(short)f2b(u2.w);
      s1[4]=(short)f2b(u3.x); s1[5]=(short)f2b(u3.y); s1[6]=(short)f2b(u3.z); s1[7]=(short)f2b(u3.w);
      *(short8*)&As[srow * 40 + skh] = s0;
      *(short8*)&As[srow * 40 + skh + 8] = s1;
    } else {
      const short8* sa = (const short8*)((const unsigned short*)Aseqv + (size_t)(m0 + srow) * 512 + k0 + skh);
      *(short8*)&As[srow * 40 + skh] = sa[0];
      *(short8*)&As[srow * 40 + skh + 8] = sa[1];
    }
    const short8* sb = (const short8*)(Wb + (size_t)(cb + srow) * 512 + k0 + skh);
    *(short8*)&Bs[srow * 40 + skh] = sb[0];
    *(short8*)&Bs[srow * 40 + skh + 8] = sb[1];
    __syncthreads();
    short8 af[2], bf[8];
    #pragma unroll
    for (int i = 0; i < 2; ++i) af[i] = *(const short8*)&As[((wid * 2 + i) * 16 + m) * 40 + q * 8];
    #pragma unroll
    for (int j = 0; j < 8; ++j) bf[j] = *(const short8*)&Bs[(j * 16 + m) * 40 + q * 8];
    #pragma unroll
    for (int i = 0; i < 2; ++i)
      #pragma unroll
      for (int j = 0; j < 8; ++j)
        acc[i][j] = __builtin_amdgcn_mfma_f32_16x16x32_bf16(af[i], bf[j], acc[i][j], 0, 0, 0);
    __syncthreads();
  }
  const bool isK = (c0 < 256);
  #pragma unroll
  for (int i = 0; i < 2; ++i) {
    #pragma unroll
    for (int j = 0; j < 8; ++j) {
      const int colg = c0 + j * 16 + m;
      const float badd = isK ? bk2[colg] : b2f(bv[colg - 256]);
      #pragma unroll
      for (int r = 0; r < 4; ++r) {
        const int mm = m0 + (wid * 2 + i) * 16 + q * 4 + r;
        const int l = mm >> 5, n = mm & 31;
        const float v = acc[i][j][r] + badd;
        const size_t o = ((size_t)n * 2048 + l) * 256 + (isK ? colg : colg - 256);
        (isK ? K2 : VALo)[o] = f2b(v);
      }
    }
  }
}

// ---------------- attention step: 256 WGs = (n, chunk-of-256-l) ----------------
__global__ __launch_bounds__(256) void k_attn(
    const int* __restrict__ seq_lens, const unsigned short* __restrict__ K2,
    const unsigned short* __restrict__ VAL, const float* __restrict__ KB,
    const unsigned short* __restrict__ h2src, float* __restrict__ ctxa_slot,
    float* __restrict__ ctxs_slot) {
  __shared__ float red[4][260];
  const int tid = threadIdx.x, wg = blockIdx.x;
  const int lane = tid & 63, wid = tid >> 6;
  const int n = wg >> 3, ch = wg & 7;
  const int len = seq_lens[n];
  const int l0 = ch << 8;
  int l1 = l0 + 256; if (l1 > len) l1 = len;
  const int hb = lane * 4;
  const float h0v = b2f(h2src[n * 256 + hb + 0]);
  const float h1v = b2f(h2src[n * 256 + hb + 1]);
  const float h2v = b2f(h2src[n * 256 + hb + 2]);
  const float h3v = b2f(h2src[n * 256 + hb + 3]);
  float a0 = 0.f, a1 = 0.f, a2 = 0.f, a3 = 0.f, se = 0.f;
  const float* kbn = KB + n * 2048;
  #pragma unroll 2
  for (int l = l0 + wid; l < l1; l += 4) {
    const size_t base = ((size_t)n * 2048 + l) * 256 + hb;
    const short4v kv = *(const short4v*)(K2 + base);
    float s = b2f((unsigned short)kv[0]) * h0v + b2f((unsigned short)kv[1]) * h1v
            + b2f((unsigned short)kv[2]) * h2v + b2f((unsigned short)kv[3]) * h3v;
    s += __shfl_xor(s, 1);  s += __shfl_xor(s, 2);  s += __shfl_xor(s, 4);
    s += __shfl_xor(s, 8);  s += __shfl_xor(s, 16); s += __shfl_xor(s, 32);
    float sc = s + kbn[l];
    sc = fminf(fmaxf(sc, -60.f), 60.f);
    const float e = __expf(sc);
    se += e;
    const short4v vv = *(const short4v*)(VAL + base);
    a0 += e * b2f((unsigned short)vv[0]); a1 += e * b2f((unsigned short)vv[1]);
    a2 += e * b2f((unsigned short)vv[2]); a3 += e * b2f((unsigned short)vv[3]);
  }
  red[wid][hb + 0] = a0; red[wid][hb + 1] = a1;
  red[wid][hb + 2] = a2; red[wid][hb + 3] = a3;
  if (lane == 0) red[wid][256] = se;
  __syncthreads();
  const float s = red[0][tid] + red[1][tid] + red[2][tid] + red[3][tid];
  atomicAdd(ctxa_slot + n * 256 + tid, s);
  if (tid == 0) {
    const float ssum = red[0][256] + red[1][256] + red[2][256] + red[3][256];
    atomicAdd(ctxs_slot + n, ssum);
  }
}

// ---------------- cell0: x = [ctx, emb(label)] ----------------
__global__ __launch_bounds__(256) void k_cell0(
    const float* __restrict__ ctxa_t, const float* __restrict__ ctxs_t,
    const int* __restrict__ label_in, int t, const unsigned short* __restrict__ emb,
    const unsigned short* __restrict__ Wih0, const unsigned short* __restrict__ Whh0,
    const unsigned short* __restrict__ bih0, const unsigned short* __restrict__ bhh0,
    const unsigned short* __restrict__ h0r, unsigned short* __restrict__ h0w,
    float* __restrict__ cst0) {
  __shared__ unsigned short lds_ctx[32 * 264];
  const int tid = threadIdx.x, wg = blockIdx.x;
  const int lane = tid & 63, wid = tid >> 6;
  for (int idx = tid; idx < 8192; idx += 256) {
    const int n = idx >> 8, k = idx & 255;
    lds_ctx[n * 264 + k] = f2b(ctxa_t[idx] / fmaxf(ctxs_t[n], 1e-30f));
  }
  __syncthreads();
  const int w = wg * 4 + wid;
  const int c = lane & 15, q = lane >> 4;
  const int grow = (c >> 2) * 256 + 4 * w + (c & 3);
  float4v ar0 = {0.f, 0.f, 0.f, 0.f}, ar1 = ar0;
  #pragma unroll
  for (int kk = 0; kk < 8; ++kk) {
    const int k = kk * 32 + q * 8;
    const short8 b = *(const short8*)(Wih0 + (size_t)grow * 512 + k);
    const short8 a0 = *(const short8*)&lds_ctx[c * 264 + k];
    const short8 a1 = *(const short8*)&lds_ctx[(c + 16) * 264 + k];
    ar0 = __builtin_amdgcn_mfma_f32_16x16x32_bf16(a0, b, ar0, 0, 0, 0);
    ar1 = __builtin_amdgcn_mfma_f32_16x16x32_bf16(a1, b, ar1, 0, 0, 0);
  }
  const int v0i = label_in[c * 200 + t];
  const int v1i = label_in[(c + 16) * 200 + t];
  const unsigned short* e0 = emb + (size_t)v0i * 256;
  const unsigned short* e1 = emb + (size_t)v1i * 256;
  #pragma unroll
  for (int kk = 0; kk < 8; ++kk) {
    const int k = kk * 32 + q * 8;
    const short8 b = *(const short8*)(Wih0 + (size_t)grow * 512 + 256 + k);
    const short8 a0 = *(const short8*)(e0 + k);
    const short8 a1 = *(const short8*)(e1 + k);
    ar0 = __builtin_amdgcn_mfma_f32_16x16x32_bf16(a0, b, ar0, 0, 0, 0);
    ar1 = __builtin_amdgcn_mfma_f32_16x16x32_bf16(a1, b, ar1, 0, 0, 0);
  }
  #pragma unroll
  for (int kk = 0; kk < 8; ++kk) {
    const int k = kk * 32 + q * 8;
    const short8 b = *(const short8*)(Whh0 + (size_t)grow * 256 + k);
    const short8 a0 = *(const short8*)(h0r + (size_t)c * 256 + k);
    const short8 a1 = *(const short8*)(h0r + (size_t)(c + 16) * 256 + k);
    ar0 = __builtin_amdgcn_mfma_f32_16x16x32_bf16(a0, b, ar0, 0, 0, 0);
    ar1 = __builtin_amdgcn_mfma_f32_16x16x32_bf16(a1, b, ar1, 0, 0, 0);
  }
  const float bias = b2f(bih0[grow]) + b2f(bhh0[grow]);
  const int d = c & 3, gt = c >> 2;
  #pragma unroll
  for (int mt = 0; mt < 2; ++mt) {
    const float4v av = mt ? ar1 : ar0;
    #pragma unroll
    for (int r = 0; r < 4; ++r) {
      const float g = av[r] + bias;
      const float gi = __shfl(g, (lane & 48) | d);
      const float gf = __shfl(g, (lane & 48) | (4 + d));
      const float gg = __shfl(g, (lane & 48) | (8 + d));
      const float go = __shfl(g, (lane & 48) | (12 + d));
      if (gt == 0) {
        const int n = mt * 16 + q * 4 + r;
        const int j = 4 * w + d;
        const float cold = cst0[n * 256 + j];
        const float cnew = sigm(gf) * cold + sigm(gi) * tanh_s(gg);
        const float hnew = sigm(go) * tanh_s(cnew);
        cst0[n * 256 + j] = cnew;
        h0w[n * 256 + j] = f2b(hnew);
      }
    }
  }
}

// ---------------- generic cell for layers 1/2 ----------------
__global__ __launch_bounds__(256) void k_cell12(
    const unsigned short* __restrict__ Wih, const unsigned short* __restrict__ Whh,
    const unsigned short* __restrict__ bih, const unsigned short* __restrict__ bhh,
    const unsigned short* __restrict__ xsrc, const unsigned short* __restrict__ hsrc,
    float* __restrict__ cstate, unsigned short* __restrict__ hdst,
    unsigned short* __restrict__ h2dst) {
  const int tid = threadIdx.x, wg = blockIdx.x;
  const int lane = tid & 63, wid = tid >> 6;
  const int w = wg * 4 + wid;
  const int c = lane & 15, q = lane >> 4;
  const int grow = (c >> 2) * 256 + 4 * w + (c & 3);
  float4v ar0 = {0.f, 0.f, 0.f, 0.f}, ar1 = ar0;
  #pragma unroll
  for (int kk = 0; kk < 8; ++kk) {
    const int k = kk * 32 + q * 8;
    const short8 b = *(const short8*)(Wih + (size_t)grow * 256 + k);
    const short8 a0 = *(const short8*)(xsrc + (size_t)c * 256 + k);
    const short8 a1 = *(const short8*)(xsrc + (size_t)(c + 16) * 256 + k);
    ar0 = __builtin_amdgcn_mfma_f32_16x16x32_bf16(a0, b, ar0, 0, 0, 0);
    ar1 = __builtin_amdgcn_mfma_f32_16x16x32_bf16(a1, b, ar1, 0, 0, 0);
  }
  #pragma unroll
  for (int kk = 0; kk < 8; ++kk) {
    const int k = kk * 32 + q * 8;
    const short8 b = *(const short8*)(Whh + (size_t)grow * 256 + k);
    const short8 a0 = *(const short8*)(hsrc + (size_t)c * 256 + k);
    const short8 a1 = *(const short8*)(hsrc + (size_t)(c + 16) * 256 + k);
    ar0 = __builtin_amdgcn_mfma_f32_16x16x32_bf16(a0, b, ar0, 0, 0, 0);
    ar1 = __builtin_amdgcn_mfma_f32_16x16x32_bf16(a1, b, ar1, 0, 0, 0);
  }
  const float bias = b2f(bih[grow]) + b2f(bhh[grow]);
  const int d = c & 3, gt = c >> 2;
  #pragma unroll
  for (int mt = 0; mt < 2; ++mt) {
    const float4v av = mt ? ar1 : ar0;
    #pragma unroll
    for (int r = 0; r < 4; ++r) {
      const float g = av[r] + bias;
      const float gi = __shfl(g, (lane & 48) | d);
      const float gf = __shfl(g, (lane & 48) | (4 + d));
      const float gg = __shfl(g, (lane & 48) | (8 + d));
      const float go = __shfl(g, (lane & 48) | (12 + d));
      if (gt == 0) {
        const int n = mt * 16 + q * 4 + r;
        const int j = 4 * w + d;
        const float cold = cstate[n * 256 + j];
        const float cnew = sigm(gf) * cold + sigm(gi) * tanh_s(gg);
        const float hnew = sigm(go) * tanh_s(cnew);
        cstate[n * 256 + j] = cnew;
        hdst[n * 256 + j] = f2b(hnew);
        if (h2dst) h2dst[n * 256 + j] = f2b(hnew);
      }
    }
  }
}

// ---------------- deferred output head (dtype-branch on write) ----------------
__global__ __launch_bounds__(256) void k_out(
    const unsigned short* __restrict__ h2all, const float* __restrict__ ctxacc,
    const float* __restrict__ ctxsum,
    const unsigned short* __restrict__ Wq, const unsigned short* __restrict__ bq,
    const unsigned short* __restrict__ Wo1, const unsigned short* __restrict__ bo1,
    const unsigned short* __restrict__ emb, const unsigned short* __restrict__ bo2,
    void* __restrict__ outv, const int* __restrict__ flag) {
  const int wg = blockIdx.x, tid = threadIdx.x;
  const int g0 = wg * 4;
  __shared__ float z[4][512];
  __shared__ float hid[4][256];
  #pragma unroll
  for (int r = 0; r < 4; ++r) hid[r][tid] = b2f(h2all[(size_t)(g0 + r) * 256 + tid]);
  __syncthreads();
  {
    float qa[4] = {0.f, 0.f, 0.f, 0.f};
    const short8* wrow = (const short8*)(Wq + (size_t)tid * 256);
    for (int k8 = 0; k8 < 32; ++k8) {
      const short8 w = wrow[k8];
      float wf[8];
      #pragma unroll
      for (int e = 0; e < 8; ++e) wf[e] = b2f((unsigned short)w[e]);
      #pragma unroll
      for (int r = 0; r < 4; ++r) {
        const float* hz = &hid[r][k8 * 8];
        const float4v x0 = *(const float4v*)hz;
        const float4v x1 = *(const float4v*)(hz + 4);
        qa[r] += wf[0] * x0.x + wf[1] * x0.y + wf[2] * x0.z + wf[3] * x0.w
               + wf[4] * x1.x + wf[5] * x1.y + wf[6] * x1.z + wf[7] * x1.w;
      }
    }
    const float bqv = b2f(bq[tid]);
    #pragma unroll
    for (int r = 0; r < 4; ++r) z[r][256 + tid] = qa[r] + bqv;
    #pragma unroll
    for (int r = 0; r < 4; ++r) {
      const int row = g0 + r; const int tt = row >> 5; const int n = row & 31;
      const float ds = fmaxf(ctxsum[(tt + 1) * 32 + n], 1e-30f);
      z[r][tid] = ctxacc[(size_t)(tt + 1) * 8192 + n * 256 + tid] / ds;
    }
  }
  __syncthreads();
  {
    float ha[4] = {0.f, 0.f, 0.f, 0.f};
    const short8* wrow = (const short8*)(Wo1 + (size_t)tid * 512);
    for (int k8 = 0; k8 < 64; ++k8) {
      const short8 w = wrow[k8];
      float wf[8];
      #pragma unroll
      for (int e = 0; e < 8; ++e) wf[e] = b2f((unsigned short)w[e]);
      #pragma unroll
      for (int r = 0; r < 4; ++r) {
        const float* hz = &z[r][k8 * 8];
        const float4v x0 = *(const float4v*)hz;
        const float4v x1 = *(const float4v*)(hz + 4);
        ha[r] += wf[0] * x0.x + wf[1] * x0.y + wf[2] * x0.z + wf[3] * x0.w
               + wf[4] * x1.x + wf[5] * x1.y + wf[6] * x1.z + wf[7] * x1.w;
      }
    }
    const float bo = b2f(bo1[tid]);
    __syncthreads();
    #pragma unroll
    for (int r = 0; r < 4; ++r) hid[r][tid] = ha[r] + bo;
  }
  __syncthreads();
  if (tid < 136) {
    const int r = tid / 34, v = tid - r * 34;
    const unsigned short* er = emb + v * 256;
    float acc = b2f(bo2[v]);
    for (int h8 = 0; h8 < 32; ++h8) {
      const short8 ee = *(const short8*)(er + h8 * 8);
      const float* hz = &hid[r][h8 * 8];
      acc += b2f((unsigned short)ee[0]) * hz[0] + b2f((unsigned short)ee[1]) * hz[1]
           + b2f((unsigned short)ee[2]) * hz[2] + b2f((unsigned short)ee[3]) * hz[3]
           + b2f((unsigned short)ee[4]) * hz[4] + b2f((unsigned short)ee[5]) * hz[5]
           + b2f((unsigned short)ee[6]) * hz[6] + b2f((unsigned short)ee[7]) * hz[7];
    }
    const size_t oidx = (size_t)(g0 + r) * 34 + v;
    if (*flag) ((unsigned short*)outv)[oidx] = f2b(acc);
    else       ((float*)outv)[oidx] = acc;
  }
}

extern "C" void kernel_launch(void* const* d_in, const int* in_sizes, int n_in,
                              void* d_out, int out_size, void* d_ws, size_t ws_size,
                              hipStream_t stream) {
  const void* seqs    = d_in[0];
  const int* seq_lens = (const int*)d_in[1];
  const int* label_in = (const int*)d_in[2];

  if (ws_size < WS_REQ) {
    k_sentinel<<<dim3((out_size + 255) / 256), dim3(256), 0, stream>>>((unsigned short*)d_out, out_size);
    return;
  }

  char* ws = (char*)d_ws;
  unsigned short* K2   = (unsigned short*)(ws + OFF_K2);
  unsigned short* VALp = (unsigned short*)(ws + OFF_VAL);
  unsigned short* Wk2  = (unsigned short*)(ws + OFF_WK2);
  float* bk2  = (float*)(ws + OFF_BK2);
  float* wkb  = (float*)(ws + OFF_WKB);
  float* bqbk = (float*)(ws + OFF_BQBK);
  float* KB   = (float*)(ws + OFF_KB);
  float* ctxa = (float*)(ws + OFF_CTXA);
  float* ctxs = (float*)(ws + OFF_CTXS);
  unsigned short* h2all = (unsigned short*)(ws + OFF_H2A);
  unsigned short* hst   = (unsigned short*)(ws + OFF_HST);
  float* cst  = (float*)(ws + OFF_CST);
  int* flag   = (int*)(ws + OFF_FLAG);

  // detect input dtype from seqs
  k_detect<<<dim3(1), dim3(64), 0, stream>>>((const unsigned*)seqs, flag);

  // convert the 24 float tensors (indices 3..26 in d_in) to bf16 ws copies
  static const size_t dsto[24] = {
    cEMB, cINITH, cINITC, cWIH0, cWHH0, cBIH0, cBHH0, cWIH1, cWHH1, cBIH1, cBHH1,
    cWIH2, cWHH2, cBIH2, cBHH2, cWQ, cBQ, cWK, cBK, cWV, cBV, cWO1, cBO1, cBO2 };
  ConvList cl;
  for (int i = 0; i < 24; ++i) {
    cl.src[i] = d_in[3 + i];
    cl.dstoff[i] = dsto[i];
    cl.n[i] = in_sizes[3 + i];
  }
  k_conv<<<dim3(2048, 24), dim3(256), 0, stream>>>(cl, ws, flag);

  const unsigned short* emb   = (const unsigned short*)(ws + cEMB);
  const unsigned short* inith = (const unsigned short*)(ws + cINITH);
  const unsigned short* initc = (const unsigned short*)(ws + cINITC);
  const unsigned short* Wih0  = (const unsigned short*)(ws + cWIH0);
  const unsigned short* Whh0  = (const unsigned short*)(ws + cWHH0);
  const unsigned short* bih0  = (const unsigned short*)(ws + cBIH0);
  const unsigned short* bhh0  = (const unsigned short*)(ws + cBHH0);
  const unsigned short* Wih1  = (const unsigned short*)(ws + cWIH1);
  const unsigned short* Whh1  = (const unsigned short*)(ws + cWHH1);
  const unsigned short* bih1  = (const unsigned short*)(ws + cBIH1);
  const unsigned short* bhh1  = (const unsigned short*)(ws + cBHH1);
  const unsigned short* Wih2  = (const unsigned short*)(ws + cWIH2);
  const unsigned short* Whh2  = (const unsigned short*)(ws + cWHH2);
  const unsigned short* bih2  = (const unsigned short*)(ws + cBIH2);
  const unsigned short* bhh2  = (const unsigned short*)(ws + cBHH2);
  const unsigned short* Wq    = (const unsigned short*)(ws + cWQ);
  const unsigned short* bq    = (const unsigned short*)(ws + cBQ);
  const unsigned short* Wk    = (const unsigned short*)(ws + cWK);
  const unsigned short* bk    = (const unsigned short*)(ws + cBK);
  const unsigned short* Wv    = (const unsigned short*)(ws + cWV);
  const unsigned short* bv    = (const unsigned short*)(ws + cBV);
  const unsigned short* Wo1   = (const unsigned short*)(ws + cWO1);
  const unsigned short* bo1   = (const unsigned short*)(ws + cBO1);
  const unsigned short* bo2   = (const unsigned short*)(ws + cBO2);

  k_p0<<<dim3(515), dim3(256), 0, stream>>>(Wq, Wk, bq, bk, Wk2, bk2, wkb, bqbk);
  k_init<<<dim3(512), dim3(256), 0, stream>>>(seqs, flag, inith, initc, wkb, bqbk, KB, ctxa, ctxs, hst, cst);
  k_gemm<<<dim3(4, 512), dim3(256), 0, stream>>>(seqs, flag, Wk2, Wv, bk2, bv, K2, VALp);

  k_attn<<<dim3(256), dim3(256), 0, stream>>>(seq_lens, K2, VALp, KB, hst + 32768, ctxa, ctxs);

  for (int t = 0; t < 200; ++t) {
    const int p = t & 1, pn = 1 - p;
    unsigned short* h0r = hst + p * 8192;
    unsigned short* h0w = hst + pn * 8192;
    unsigned short* h1r = hst + 16384 + p * 8192;
    unsigned short* h1w = hst + 16384 + pn * 8192;
    unsigned short* h2r = hst + 32768 + p * 8192;
    unsigned short* h2w = hst + 32768 + pn * 8192;

    k_cell0<<<dim3(16), dim3(256), 0, stream>>>(ctxa + (size_t)t * 8192, ctxs + (size_t)t * 32,
                                                label_in, t, emb, Wih0, Whh0, bih0, bhh0,
                                                h0r, h0w, cst);
    k_cell12<<<dim3(16), dim3(256), 0, stream>>>(Wih1, Whh1, bih1, bhh1, h0w, h1r,
                                                 cst + 8192, h1w, (unsigned short*)nullptr);
    k_cell12<<<dim3(16), dim3(256), 0, stream>>>(Wih2, Whh2, bih2, bhh2, h1w, h2r,
                                                 cst + 16384, h2w, h2all + (size_t)t * 8192);
    k_attn<<<dim3(256), dim3(256), 0, stream>>>(seq_lens, K2, VALp, KB, h2w,
                                                ctxa + (size_t)(t + 1) * 8192,
                                                ctxs + (size_t)(t + 1) * 32);
  }

  k_out<<<dim3(1600), dim3(256), 0, stream>>>(h2all, ctxa, ctxs, Wq, bq, Wo1, bo1, emb, bo2, d_out, flag);
}